// Round 4
// baseline (122.422 us; speedup 1.0000x reference)
//
#include <hip/hip_runtime.h>
#include <hip/hip_bf16.h>

// PositionalBias: pbv[n,j,h,d] = sum_{l=1..2046} w[h,|j-l|] * v[n,l,h,d]  (j in 1..2046, else 0)
//                 z_pb[l,h]    = sum_{j=1..2046} w[h,|l-j|]               (l in 1..2046, else 0)
// B=4, S=2048, H=12, D=64. Outputs fp32: pbv (6291456) then z_pb (24576).
//
// TWO dispatches:
//  1) prep_kernel (792 blocks):
//     0..767  : LDS-transpose+convert v -> g_vt[n][h][d][l] bf16 (128-l x 64-d tile per
//               block; padded-stride LDS transpose -> full-line coalesced global writes),
//               borders l=0/2047 zeroed
//     768..779: z_pb
//     780..791: A fragment table g_wt: F[h][8q+i] = bf16(w_ext[2174 - q - i]).
//  2) gemm_kernel (768 blocks, 4 blocks/CU): per block, copy its 2304-slot A-window from
//     g_wt into LDS (coalesced), then per iter per wave: 4 ds_read_b128 (A, 2-way alias =
//     free) + 2 global dwordx4 (B, distance-2) + 16 MFMA under setprio.

typedef short short8 __attribute__((ext_vector_type(8)));   // 8 x bf16 bits (4 VGPRs)
typedef float floatx4 __attribute__((ext_vector_type(4)));  // MFMA accumulator
typedef unsigned uint4_ __attribute__((ext_vector_type(4)));

#define QN 4352   // A-table fragment slots per h; max read = (2047-0)+2303 = 4350

__device__ __attribute__((aligned(16))) short g_vt[4 * 12 * 64 * 2048];  // 12.6 MB
__device__ __attribute__((aligned(16))) short g_wt[12 * QN * 8];         // 835 KB

__device__ __forceinline__ unsigned short f2bf(float f) {
  union { __hip_bfloat16 b; unsigned short u; } cv;
  cv.b = __float2bfloat16(f);  // RNE
  return cv.u;
}

// ---------------- dispatch 1: v -> g_vt (LDS transpose), z_pb, w -> g_wt ----------------
__global__ __launch_bounds__(256) void prep_kernel(const float* __restrict__ v,
                                                   const float* __restrict__ w,
                                                   float* __restrict__ out) {
  __shared__ unsigned tls[64 * 65];   // transpose tile: [d][l-pair], pad->2-way only
  __shared__ float zls[4096];
  __shared__ float wsum[4];

  const int bx  = blockIdx.x;
  const int tid = threadIdx.x;

  if (bx >= 780) {   // ---- A fragment table for h = bx-780 ----
    const int h = bx - 780;
    const float* wh = w + (size_t)h * 2048;
    short* F = g_wt + (size_t)h * QN * 8;
    for (int q = tid; q < QN; q += 256) {
      unsigned short buf[8] __attribute__((aligned(16)));
      #pragma unroll
      for (int i = 0; i < 8; ++i) {
        int t = 2174 - q - i;
        int a = t < 0 ? -t : t;
        buf[i] = (a <= 2045) ? f2bf(wh[a]) : (unsigned short)0;
      }
      *(short8*)&F[(size_t)q * 8] = *(const short8*)buf;
    }
    return;
  }

  if (bx >= 768) {   // ---- zpb: z[i+1] = P[i] + P[2045-i] - w[h,0] ----
    const int h = bx - 768;
    float* wvv = zls;          // [2048]
    float* pfx = zls + 2048;   // [2048]
    const float* wh = w + (size_t)h * 2048;
    float* zout = out + 6291456;
    for (int i = tid; i < 2048; i += 256) wvv[i] = (i < 2046) ? wh[i] : 0.f;
    __syncthreads();
    const int base = tid * 8;
    float run0 = 0.f;
    #pragma unroll
    for (int k = 0; k < 8; ++k) run0 += wvv[base + k];
    float x = run0;
    #pragma unroll
    for (int dd = 1; dd < 64; dd <<= 1) {
      float y = __shfl_up(x, dd);
      if ((tid & 63) >= dd) x += y;
    }
    if ((tid & 63) == 63) wsum[tid >> 6] = x;
    __syncthreads();
    const int wid4 = tid >> 6;
    float woff = 0.f;
    #pragma unroll
    for (int u = 0; u < 3; ++u) { float t = wsum[u]; if (u < wid4) woff += t; }
    float pr = x + woff - run0;
    #pragma unroll
    for (int k = 0; k < 8; ++k) { pr += wvv[base + k]; pfx[base + k] = pr; }
    __syncthreads();
    for (int i = tid; i < 2046; i += 256) {
      float z = pfx[i] + pfx[2045 - i] - wvv[0];
      zout[(size_t)(i + 1) * 12 + h] = z;
    }
    if (tid == 0) { zout[h] = 0.f; zout[(size_t)2047 * 12 + h] = 0.f; }
    return;
  }

  // ---- transpose: block = (n, h, 128-l chunk). Wave reads 32 l x 64 d (coalesced),
  //      LDS-transposes, then threads store full 64B lines per d-row. ----
  const int chunk = bx & 15;            // 16 chunks of 128 l
  const int slice = bx >> 4;            // 0..47
  const int n = slice / 12, h = slice - n * 12;
  const int lane = tid & 63;            // d on read side
  const int wv   = tid >> 6;            // 0..3
  const int lbase = chunk * 128 + wv * 32;

  const float* src = v + (((size_t)n * 2048 + lbase) * 12 + h) * 64 + lane;
  #pragma unroll
  for (int kk = 0; kk < 16; ++kk) {
    float f0 = src[(size_t)(2 * kk)     * 768];
    float f1 = src[(size_t)(2 * kk + 1) * 768];
    int l = lbase + 2 * kk;
    unsigned lo = (l == 0)        ? 0u : (unsigned)f2bf(f0);
    unsigned hi = (l + 1 == 2047) ? 0u : (unsigned)f2bf(f1);
    tls[lane * 65 + wv * 16 + kk] = lo | (hi << 16);
  }
  __syncthreads();

  const int r = tid >> 2;               // d-row on store side
  const int m = tid & 3;                // 64B segment within row
  unsigned xbuf[16];
  #pragma unroll
  for (int k = 0; k < 16; ++k) xbuf[k] = tls[r * 65 + m * 16 + k];
  unsigned* dstu = (unsigned*)(g_vt + (((size_t)n * 12 + h) * 64 + r) * 2048 +
                               (size_t)chunk * 128) + m * 16;
  #pragma unroll
  for (int k4 = 0; k4 < 4; ++k4) {
    uint4_ val = {xbuf[k4 * 4], xbuf[k4 * 4 + 1], xbuf[k4 * 4 + 2], xbuf[k4 * 4 + 3]};
    *(uint4_*)&dstu[k4 * 4] = val;
  }
}

// ---------------- dispatch 2: Toeplitz GEMM, 128j x 64nd per block, 4 blocks/CU ----------
__global__ __launch_bounds__(256, 4) void gemm_kernel(float* __restrict__ out) {
  __shared__ __attribute__((aligned(16))) short Als[2304 * 8];  // 36,864 B

  const int bx  = blockIdx.x;
  const int tid = threadIdx.x;

  // Same-slice blocks are 48 apart (48%8==0) -> same XCD -> vt-slice + A-window L2-resident.
  const int slice = bx % 48;          // (h, ndt)
  const int jt    = bx / 48;          // 16 j-tiles
  const int ndt = slice & 3;
  const int h   = slice >> 2;
  const int lane = tid & 63;
  const int wid  = tid >> 6;
  const int lm = lane & 15, quad = lane >> 4;
  const int jb = jt * 128;
  const int d  = wid * 16 + lm;       // wave owns a 16-d strip

  // B: bf16 v^T row (borders pre-zeroed). One dwordx4 IS the B-fragment.
  const short* vtb = g_vt + (((size_t)ndt * 12 + h) * 64 + d) * 2048;
  auto load_bf = [&](int lb) -> short8 {
    return *(const short8*)&vtb[lb];
  };

  // issue t=0,1 B-frags first: latency hides under the A-window copy
  short8 bc0 = load_bf(quad * 8);
  short8 bc1 = load_bf(32 + quad * 8);
  short8 bn0 = load_bf(64 + quad * 8);
  short8 bn1 = load_bf(96 + quad * 8);

  // copy this block's A-window g_wt[h][qbase .. qbase+2303] -> LDS (coalesced, no VALU)
  const short* wsrc = g_wt + (size_t)h * QN * 8 + (size_t)(2047 - jb) * 8;
  #pragma unroll
  for (int k = 0; k < 9; ++k) {
    *(short8*)&Als[(size_t)(k * 256 + tid) * 8] =
        *(const short8*)&wsrc[(size_t)(k * 256 + tid) * 8];
  }
  __syncthreads();   // the only block-wide sync

  // A-frag at slot p+abase (16B each): value_i = w_ext[j - k] for this lane's (quad,lm).
  // p = l0 + 16*g, abase = 127 + quad*8 - lm; lanes lm/lm+8 alias banks -> 2-way (free).
  const int abase = 127 + quad * 8 - lm;
  auto load_af = [&](int p) -> short8 {
    return *(const short8*)&Als[(size_t)(p + abase) * 8];
  };

  short8 afr[10];                      // afr[i] = diagonal g = i-7 relative to current l0
  #pragma unroll
  for (int i = 0; i < 10; ++i) afr[i] = load_af((i - 7) * 16);

  floatx4 acc[8];
  #pragma unroll
  for (int ma = 0; ma < 8; ++ma) acc[ma] = (floatx4){0.f, 0.f, 0.f, 0.f};

  #pragma unroll 4
  for (int t = 0; t < 32; ++t) {
    const int l0 = t * 64;
    // B prefetch distance 2 (branchless clamp; tail re-reads t=31: harmless)
    int t2 = t + 2; if (t2 > 31) t2 = 31;
    const int lb = t2 * 64 + quad * 8;
    short8 bm0 = load_bf(lb);
    short8 bm1 = load_bf(lb + 32);
    // A prefetch distance 1: next iter's fresh diagonals g = -1,0,1,2
    const int l0n = (t < 31) ? l0 + 64 : l0;
    short8 na0 = load_af(l0n - 16);
    short8 na1 = load_af(l0n);
    short8 na2 = load_af(l0n + 16);
    short8 na3 = load_af(l0n + 32);

    __builtin_amdgcn_s_setprio(1);
    #pragma unroll
    for (int ma = 0; ma < 8; ++ma)   // kc=0: g = -ma  -> idx 7-ma
      acc[ma] = __builtin_amdgcn_mfma_f32_16x16x32_bf16(afr[7 - ma], bc0, acc[ma], 0, 0, 0);
    #pragma unroll
    for (int ma = 0; ma < 8; ++ma)   // kc=1: g = 2-ma -> idx 9-ma
      acc[ma] = __builtin_amdgcn_mfma_f32_16x16x32_bf16(afr[9 - ma], bc1, acc[ma], 0, 0, 0);
    __builtin_amdgcn_s_setprio(0);

    // rotate pipelines
    #pragma unroll
    for (int i = 0; i < 6; ++i) afr[i] = afr[i + 4];
    afr[6] = na0; afr[7] = na1; afr[8] = na2; afr[9] = na3;
    bc0 = bn0; bc1 = bn1;
    bn0 = bm0; bn1 = bm1;
  }

  // epilogue: D row = quad*4 + r (j), col = lm (d); zero rows j=0 and j=2047
  float* obase = out + (size_t)ndt * 1572864 + (size_t)h * 64 + d;
  #pragma unroll
  for (int ma = 0; ma < 8; ++ma) {
    floatx4 cc = acc[ma];
    #pragma unroll
    for (int r = 0; r < 4; ++r) {
      int j = jb + ma * 16 + quad * 4 + r;
      float val = (j == 0 || j == 2047) ? 0.f : cc[r];
      obase[(size_t)j * 768] = val;
    }
  }
}

extern "C" void kernel_launch(void* const* d_in, const int* in_sizes, int n_in,
                              void* d_out, int out_size, void* d_ws, size_t ws_size,
                              hipStream_t stream) {
  const float* v = (const float*)d_in[0];   // (4,2048,12,64) fp32
  const float* w = (const float*)d_in[1];   // (12,2048) fp32
  float* out = (float*)d_out;               // pbv (6291456) + z_pb (24576) fp32
  prep_kernel<<<dim3(792), 256, 0, stream>>>(v, w, out);
  gemm_kernel<<<dim3(768), 256, 0, stream>>>(out);
}

// Round 5
// 120.834 us; speedup vs baseline: 1.0131x; 1.0131x over previous
//
#include <hip/hip_runtime.h>
#include <hip/hip_bf16.h>

// PositionalBias: pbv[n,j,h,d] = sum_{l=1..2046} w[h,|j-l|] * v[n,l,h,d]  (j in 1..2046, else 0)
//                 z_pb[l,h]    = sum_{j=1..2046} w[h,|l-j|]               (l in 1..2046, else 0)
// B=4, S=2048, H=12, D=64. Outputs fp32: pbv (6291456) then z_pb (24576).
//
// SINGLE-DISPATCH fused kernel (780 blocks): 0..767 Toeplitz GEMM, 768..779 z_pb.
// GEMM block (128j x 64nd, 4 waves x 128j x 16d strips):
//  - A: per-block 8x-shifted reversed-Toeplitz bf16 table in LDS (built once from w,
//       ~71 f2bf/thread, overlapped with the t=0/1 B-loads already in flight); inner
//       reads are aligned ds_read_b128 on a 10-frag sliding diagonal window.
//  - B: fp32 v loaded straight to registers (16 scalar dwords/iter, coalesced 64B/quad),
//       FULL-UNROLL distance-2 pipeline (static SSA - nothing for the scheduler to
//       collapse), packed to bf16 with bare paired cvt (borders l=0/2047 specialized
//       into iterations 0 and 30 only: 2 predicated ops total).
//  - 16 MFMA 16x16x32 per iter under setprio.

typedef short short8 __attribute__((ext_vector_type(8)));   // 8 x bf16 bits (4 VGPRs)
typedef float floatx4 __attribute__((ext_vector_type(4)));  // MFMA accumulator

#define TL 2280   // A-table length per shifted copy (shorts); 8 copies = 36.5 KB LDS

__device__ __forceinline__ unsigned short f2bf(float f) {
  union { __hip_bfloat16 b; unsigned short u; } cv;
  cv.b = __float2bfloat16(f);  // RNE
  return cv.u;
}

__global__ __launch_bounds__(256, 3) void fused_kernel(const float* __restrict__ v,
                                                       const float* __restrict__ w,
                                                       float* __restrict__ out) {
  __shared__ __attribute__((aligned(16))) short Tls[8 * TL];  // 36.5 KB (aliased by zpb)

  const int bx  = blockIdx.x;
  const int tid = threadIdx.x;

  if (bx >= 768) {   // ---------------- zpb: z[i+1] = P[i] + P[2045-i] - w[h,0] ----------------
    const int h = bx - 768;
    float* wv  = (float*)Tls;          // [2048]
    float* pfx = ((float*)Tls) + 2048; // [2048]
    __shared__ float wsum[4];
    const float* wh = w + (size_t)h * 2048;
    float* zout = out + 6291456;
    for (int i = tid; i < 2048; i += 256) wv[i] = (i < 2046) ? wh[i] : 0.f;
    __syncthreads();
    const int base = tid * 8;
    float run0 = 0.f;
    #pragma unroll
    for (int k = 0; k < 8; ++k) run0 += wv[base + k];
    float x = run0;
    #pragma unroll
    for (int dd = 1; dd < 64; dd <<= 1) {
      float y = __shfl_up(x, dd);
      if ((tid & 63) >= dd) x += y;
    }
    if ((tid & 63) == 63) wsum[tid >> 6] = x;
    __syncthreads();
    const int wid4 = tid >> 6;
    float woff = 0.f;
    #pragma unroll
    for (int u = 0; u < 3; ++u) { float t = wsum[u]; if (u < wid4) woff += t; }
    float pr = x + woff - run0;
    #pragma unroll
    for (int k = 0; k < 8; ++k) { pr += wv[base + k]; pfx[base + k] = pr; }
    __syncthreads();
    for (int i = tid; i < 2046; i += 256) {
      float z = pfx[i] + pfx[2045 - i] - wv[0];
      zout[(size_t)(i + 1) * 12 + h] = z;
    }
    if (tid == 0) { zout[h] = 0.f; zout[(size_t)2047 * 12 + h] = 0.f; }
    return;
  }

  // ---------------- GEMM block ----------------
  // Same-slice blocks are 48 apart (48%8==0) -> same XCD -> v-slice L2-resident.
  const int slice = bx % 48;          // (h, ndt)
  const int jt    = bx / 48;          // 16 j-tiles
  const int ndt = slice & 3;
  const int h   = slice >> 2;
  const int lane = tid & 63, wid = tid >> 6;
  const int lm = lane & 15, quad = lane >> 4;
  const int jb = jt * 128;
  const int d  = wid * 16 + lm;       // wave owns a 16-d strip

  // B source: v[ndt][l][h][d], l-stride 768 floats. Per instr: 4 quads x 16 consecutive d
  // = 4 fully-used 64B segments.
  const float* vrow = v + (((size_t)ndt * 2048) * 12 + h) * 64 + d;

  // raw fp32 B for t=0,1 issued BEFORE the table build (latency hides under build VALU)
  float r0[16], rA[16];
  {
    const int lb = quad * 8;
    #pragma unroll
    for (int i = 0; i < 8; ++i) r0[i]     = vrow[(size_t)(lb + i) * 768];
    #pragma unroll
    for (int i = 0; i < 8; ++i) r0[8 + i] = vrow[(size_t)(lb + 32 + i) * 768];
    #pragma unroll
    for (int i = 0; i < 8; ++i) rA[i]     = vrow[(size_t)(64 + lb + i) * 768];
    #pragma unroll
    for (int i = 0; i < 8; ++i) rA[8 + i] = vrow[(size_t)(64 + 32 + lb + i) * 768];
  }

  // build reversed, 8x-shifted Toeplitz table: T_c[p] = w_ext[127 + jb - p - c]
  const float* wh = w + (size_t)h * 2048;
  for (int g = tid; g < 8 * (TL / 8); g += 256) {
    int c  = g / (TL / 8);
    int p8 = (g - c * (TL / 8)) * 8;
    unsigned short buf[8] __attribute__((aligned(16)));
    #pragma unroll
    for (int i = 0; i < 8; ++i) {
      int t = 127 + jb - (p8 + i) - c;
      int a = t < 0 ? -t : t;
      buf[i] = (a <= 2045) ? f2bf(wh[a]) : (unsigned short)0;
    }
    *(short8*)&Tls[c * TL + p8] = *(const short8*)buf;
  }
  __syncthreads();   // the only block-wide sync

  // A-frag at slot p+abase: value_i = w_ext[j - k]; aligned b128 via copy (p0 & 7).
  const int abase = 127 + quad * 8 - lm;
  auto load_af = [&](int p) -> short8 {
    int p0 = p + abase;
    int c = p0 & 7;
    return *(const short8*)&Tls[c * TL + (p0 - c)];
  };

  // bare pack (no border masks in generic path; compiler pairs to v_cvt_pk_bf16_f32)
  auto packB = [&](const float* f, short8& b0, short8& b1) {
    #pragma unroll
    for (int i = 0; i < 8; ++i) {
      b0[i] = (short)f2bf(f[i]);
      b1[i] = (short)f2bf(f[8 + i]);
    }
  };

  short8 afr[10];                      // afr[i] = diagonal g = i-7 relative to current l0
  #pragma unroll
  for (int i = 0; i < 10; ++i) afr[i] = load_af((i - 7) * 16);

  short8 bc0, bc1;
  packB(r0, bc0, bc1);
  if (quad == 0) bc0[0] = 0;           // l = 0 border (only t=0, quad0, elem0)

  floatx4 acc[8];
  #pragma unroll
  for (int ma = 0; ma < 8; ++ma) acc[ma] = (floatx4){0.f, 0.f, 0.f, 0.f};

  #pragma unroll                        // FULL unroll: static pipeline, nothing collapsible
  for (int t = 0; t < 32; ++t) {
    // raw B loads for t+2
    float rN[16];
    if (t < 30) {
      const int lb2 = (t + 2) * 64 + quad * 8;
      #pragma unroll
      for (int i = 0; i < 8; ++i) rN[i]     = vrow[(size_t)(lb2 + i) * 768];
      #pragma unroll
      for (int i = 0; i < 8; ++i) rN[8 + i] = vrow[(size_t)(lb2 + 32 + i) * 768];
    }
    // A prefetch distance 1: next iter's fresh diagonals g = -1,0,1,2
    short8 na0, na1, na2, na3;
    if (t < 31) {
      const int l0n = t * 64 + 64;
      na0 = load_af(l0n - 16);
      na1 = load_af(l0n);
      na2 = load_af(l0n + 16);
      na3 = load_af(l0n + 32);
    }

    __builtin_amdgcn_s_setprio(1);
    #pragma unroll
    for (int ma = 0; ma < 8; ++ma)   // kc=0: g = -ma  -> idx 7-ma
      acc[ma] = __builtin_amdgcn_mfma_f32_16x16x32_bf16(afr[7 - ma], bc0, acc[ma], 0, 0, 0);
    #pragma unroll
    for (int ma = 0; ma < 8; ++ma)   // kc=1: g = 2-ma -> idx 9-ma
      acc[ma] = __builtin_amdgcn_mfma_f32_16x16x32_bf16(afr[9 - ma], bc1, acc[ma], 0, 0, 0);
    __builtin_amdgcn_s_setprio(0);

    if (t < 31) {
      // pack rA (raw of t+1, in flight ~2 iters) -> B for next iter
      short8 nb0, nb1;
      packB(rA, nb0, nb1);
      if (t == 30 && quad == 3) nb1[7] = 0;   // l = 2047 border (t=31, bc1, quad3, elem7)
      bc0 = nb0; bc1 = nb1;
      // slide A window by 4 diagonals; rotate raw-B pipeline
      #pragma unroll
      for (int i = 0; i < 6; ++i) afr[i] = afr[i + 4];
      afr[6] = na0; afr[7] = na1; afr[8] = na2; afr[9] = na3;
      if (t < 30) {
        #pragma unroll
        for (int i = 0; i < 16; ++i) rA[i] = rN[i];
      }
    }
  }

  // epilogue: D row = quad*4 + r (j), col = lm (d); zero rows j=0 and j=2047
  float* obase = out + (size_t)ndt * 1572864 + (size_t)h * 64 + d;
  #pragma unroll
  for (int ma = 0; ma < 8; ++ma) {
    floatx4 cc = acc[ma];
    #pragma unroll
    for (int r = 0; r < 4; ++r) {
      int j = jb + ma * 16 + quad * 4 + r;
      float val = (j == 0 || j == 2047) ? 0.f : cc[r];
      obase[(size_t)j * 768] = val;
    }
  }
}

extern "C" void kernel_launch(void* const* d_in, const int* in_sizes, int n_in,
                              void* d_out, int out_size, void* d_ws, size_t ws_size,
                              hipStream_t stream) {
  const float* v = (const float*)d_in[0];   // (4,2048,12,64) fp32
  const float* w = (const float*)d_in[1];   // (12,2048) fp32
  float* out = (float*)d_out;               // pbv (6291456) + z_pb (24576) fp32
  fused_kernel<<<dim3(780), 256, 0, stream>>>(v, w, out);
}

// Round 6
// 118.146 us; speedup vs baseline: 1.0362x; 1.0227x over previous
//
#include <hip/hip_runtime.h>
#include <hip/hip_bf16.h>

// PositionalBias: pbv[n,j,h,d] = sum_{l=1..2046} w[h,|j-l|] * v[n,l,h,d]  (j in 1..2046, else 0)
//                 z_pb[l,h]    = sum_{j=1..2046} w[h,|l-j|]               (l in 1..2046, else 0)
// B=4, S=2048, H=12, D=64. Outputs fp32: pbv (6291456) then z_pb (24576).
//
// SINGLE-DISPATCH fused kernel, 780 blocks x 128 threads:
//   blocks 0..767 = Toeplitz GEMM, blocks 768..779 = z_pb.
// GEMM block = TWO j-tiles (256 j) x 32 d, 2 waves x 16-d strips. Toeplitz key idea:
// the second j-tile's diagonal window is the first's shifted by 8 fragments, so ONE
// contiguous 18-frag sliding window (72 VGPR) serves both -> per iter per wave:
// 16 B scalar loads + 4 fresh ds_read_b128 + 16 cvt feed 32 MFMAs (2x the MFMA density
// per byte loaded vs the 1-tile version that measured MfmaUtil=15%).
//  - A: per-block 8x-shifted reversed-Toeplitz bf16 table in LDS (built once, 36.9 KB),
//       aligned ds_read_b128, 2-way bank alias only.
//  - B: fp32 v -> registers (coalesced 64B/quad), distance-1, packed to bf16 with paired
//       cvt; borders l=0/2047 specialized to single predicated ops at t=0 / t=30.
//  - 32 MFMA 16x16x32 per iter under setprio; grid 768 = even 3 blocks/CU.

typedef short short8 __attribute__((ext_vector_type(8)));   // 8 x bf16 bits (4 VGPRs)
typedef float floatx4 __attribute__((ext_vector_type(4)));  // MFMA accumulator

#define TL 2304   // A-table length per shifted copy (shorts); 8 copies = 36,864 B LDS

__device__ __forceinline__ unsigned short f2bf(float f) {
  union { __hip_bfloat16 b; unsigned short u; } cv;
  cv.b = __float2bfloat16(f);  // RNE
  return cv.u;
}

__global__ __launch_bounds__(128, 2) void fused_kernel(const float* __restrict__ v,
                                                       const float* __restrict__ w,
                                                       float* __restrict__ out) {
  __shared__ __attribute__((aligned(16))) short Tls[8 * TL];  // 36,864 B (aliased by zpb)

  const int bx  = blockIdx.x;
  const int tid = threadIdx.x;

  if (bx >= 768) {   // ---------------- zpb: z[i+1] = P[i] + P[2045-i] - w[h,0] -------------
    const int h = bx - 768;
    float* wv  = (float*)Tls;          // [2048]
    float* pfx = ((float*)Tls) + 2048; // [2048]
    __shared__ float wsum[2];
    const float* wh = w + (size_t)h * 2048;
    float* zout = out + 6291456;
    for (int i = tid; i < 2048; i += 128) wv[i] = (i < 2046) ? wh[i] : 0.f;
    __syncthreads();
    const int base = tid * 16;
    float run0 = 0.f;
    #pragma unroll
    for (int k = 0; k < 16; ++k) run0 += wv[base + k];
    float x = run0;
    #pragma unroll
    for (int dd = 1; dd < 64; dd <<= 1) {
      float y = __shfl_up(x, dd);
      if ((tid & 63) >= dd) x += y;
    }
    if ((tid & 63) == 63) wsum[tid >> 6] = x;
    __syncthreads();
    float woff = (tid >> 6) ? wsum[0] : 0.f;
    float pr = x + woff - run0;
    #pragma unroll
    for (int k = 0; k < 16; ++k) { pr += wv[base + k]; pfx[base + k] = pr; }
    __syncthreads();
    for (int i = tid; i < 2046; i += 128) {
      float z = pfx[i] + pfx[2045 - i] - wv[0];
      zout[(size_t)(i + 1) * 12 + h] = z;
    }
    if (tid == 0) { zout[h] = 0.f; zout[(size_t)2047 * 12 + h] = 0.f; }
    return;
  }

  // ---------------- GEMM block: 256j x 32d; 2 waves own 256j x 16d strips ----------------
  // Same-slice blocks are 48 apart (48%8==0) -> same XCD -> v-slice L2-resident.
  const int slice = bx % 48;          // (h, ndt)
  const int rest  = bx / 48;          // 0..15
  const int jp    = rest >> 1;        // j-pair 0..7
  const int dh    = rest & 1;         // d-half 0..1
  const int ndt = slice & 3;
  const int h   = slice >> 2;
  const int lane = tid & 63, wid = tid >> 6;   // wid in {0,1}
  const int lm = lane & 15, quad = lane >> 4;
  const int jb = jp * 256;
  const int d  = dh * 32 + wid * 16 + lm;      // lane's head-dim index

  // B source: v[ndt][l][h][d], l-stride 768 floats. Per instr: 4 quads x 16 consecutive d
  // = 4 fully-used 64B segments.
  const float* vrow = v + (((size_t)ndt * 2048) * 12 + h) * 64 + d;

  // raw fp32 B for t=0 issued BEFORE the table build (latency hides under build VALU)
  float r0[16];
  {
    const int lb = quad * 8;
    #pragma unroll
    for (int i = 0; i < 8; ++i) r0[i]     = vrow[(size_t)(lb + i) * 768];
    #pragma unroll
    for (int i = 0; i < 8; ++i) r0[8 + i] = vrow[(size_t)(lb + 32 + i) * 768];
  }

  // build reversed, 8x-shifted Toeplitz table: T_c[p] = w_ext[255 + jb - p - c]
  // (origin +128 vs the 1-tile version so the second j-tile's window stays at p >= 0)
  const float* wh = w + (size_t)h * 2048;
  for (int g = tid; g < 8 * (TL / 8); g += 128) {
    int c  = g / (TL / 8);
    int p8 = (g - c * (TL / 8)) * 8;
    unsigned short buf[8] __attribute__((aligned(16)));
    #pragma unroll
    for (int i = 0; i < 8; ++i) {
      int t = 255 + jb - (p8 + i) - c;
      int a = t < 0 ? -t : t;
      buf[i] = (a <= 2045) ? f2bf(wh[a]) : (unsigned short)0;
    }
    *(short8*)&Tls[c * TL + p8] = *(const short8*)buf;
  }
  __syncthreads();   // the only block-wide sync

  // A-frag at diagonal g (16-slot spacing), k-base l0: value_i = w_ext[j - k];
  // p0 = l0 + 16*g + ABASE, aligned b128 from copy (p0 & 7).
  // j-tile 0 (j = jb + ...): kc=0 -> g = -ma     ; kc=1 -> g = 2-ma    (afr idx g+15)
  // j-tile 1 (j += 128)    : kc=0 -> g = -8-ma   ; kc=1 -> g = -6-ma
  const int ABASE = 255 + quad * 8 - lm;
  auto load_af = [&](int p) -> short8 {
    int p0 = p + ABASE;
    int c = p0 & 7;
    return *(const short8*)&Tls[c * TL + (p0 - c)];
  };

  // bare pack (compiler pairs to v_cvt_pk_bf16_f32)
  auto packB = [&](const float* f, short8& b0, short8& b1) {
    #pragma unroll
    for (int i = 0; i < 8; ++i) {
      b0[i] = (short)f2bf(f[i]);
      b1[i] = (short)f2bf(f[8 + i]);
    }
  };

  short8 afr[18];                      // afr[i] = diagonal g = i-15 relative to current l0
  #pragma unroll
  for (int i = 0; i < 18; ++i) afr[i] = load_af((i - 15) * 16);

  short8 bc0, bc1;
  packB(r0, bc0, bc1);
  if (quad == 0) bc0[0] = 0;           // l = 0 border (t=0, quad0, elem0)

  floatx4 acc0[8], acc1[8];
  #pragma unroll
  for (int ma = 0; ma < 8; ++ma) {
    acc0[ma] = (floatx4){0.f, 0.f, 0.f, 0.f};
    acc1[ma] = (floatx4){0.f, 0.f, 0.f, 0.f};
  }

  #pragma unroll 4
  for (int t = 0; t < 32; ++t) {
    // B loads for t+1 (distance-1: the 32-MFMA cluster below covers L2 latency)
    float rN[16];
    if (t < 31) {
      const int lb2 = (t + 1) * 64 + quad * 8;
      #pragma unroll
      for (int i = 0; i < 8; ++i) rN[i]     = vrow[(size_t)(lb2 + i) * 768];
      #pragma unroll
      for (int i = 0; i < 8; ++i) rN[8 + i] = vrow[(size_t)(lb2 + 32 + i) * 768];
    }
    // A prefetch distance 1: next iter's fresh diagonals g = -1,0,1,2
    short8 na0, na1, na2, na3;
    if (t < 31) {
      const int l0n = t * 64 + 64;
      na0 = load_af(l0n - 16);
      na1 = load_af(l0n);
      na2 = load_af(l0n + 16);
      na3 = load_af(l0n + 32);
    }

    __builtin_amdgcn_s_setprio(1);
    #pragma unroll
    for (int ma = 0; ma < 8; ++ma)   // tile0 kc=0: g = -ma   -> idx 15-ma
      acc0[ma] = __builtin_amdgcn_mfma_f32_16x16x32_bf16(afr[15 - ma], bc0, acc0[ma], 0, 0, 0);
    #pragma unroll
    for (int ma = 0; ma < 8; ++ma)   // tile1 kc=0: g = -8-ma -> idx 7-ma
      acc1[ma] = __builtin_amdgcn_mfma_f32_16x16x32_bf16(afr[7 - ma], bc0, acc1[ma], 0, 0, 0);
    #pragma unroll
    for (int ma = 0; ma < 8; ++ma)   // tile0 kc=1: g = 2-ma  -> idx 17-ma
      acc0[ma] = __builtin_amdgcn_mfma_f32_16x16x32_bf16(afr[17 - ma], bc1, acc0[ma], 0, 0, 0);
    #pragma unroll
    for (int ma = 0; ma < 8; ++ma)   // tile1 kc=1: g = -6-ma -> idx 9-ma
      acc1[ma] = __builtin_amdgcn_mfma_f32_16x16x32_bf16(afr[9 - ma], bc1, acc1[ma], 0, 0, 0);
    __builtin_amdgcn_s_setprio(0);

    if (t < 31) {
      // pack rN -> B for next iter
      short8 nb0, nb1;
      packB(rN, nb0, nb1);
      if (t == 30 && quad == 3) nb1[7] = 0;   // l = 2047 border (t=31, bc1, quad3, elem7)
      bc0 = nb0; bc1 = nb1;
      // slide the 18-frag window by 4 diagonals
      #pragma unroll
      for (int i = 0; i < 14; ++i) afr[i] = afr[i + 4];
      afr[14] = na0; afr[15] = na1; afr[16] = na2; afr[17] = na3;
    }
  }

  // epilogue: D row = quad*4 + r (j), col = lm (d); zero rows j=0 and j=2047
  float* obase = out + (size_t)ndt * 1572864 + (size_t)h * 64 + d;
  #pragma unroll
  for (int ma = 0; ma < 8; ++ma) {
    floatx4 c0 = acc0[ma];
    floatx4 c1 = acc1[ma];
    #pragma unroll
    for (int r = 0; r < 4; ++r) {
      int j0 = jb + ma * 16 + quad * 4 + r;
      int j1 = j0 + 128;
      float v0 = (j0 == 0) ? 0.f : c0[r];
      float v1 = (j1 == 2047) ? 0.f : c1[r];
      obase[(size_t)j0 * 768] = v0;
      obase[(size_t)j1 * 768] = v1;
    }
  }
}

extern "C" void kernel_launch(void* const* d_in, const int* in_sizes, int n_in,
                              void* d_out, int out_size, void* d_ws, size_t ws_size,
                              hipStream_t stream) {
  const float* v = (const float*)d_in[0];   // (4,2048,12,64) fp32
  const float* w = (const float*)d_in[1];   // (12,2048) fp32
  float* out = (float*)d_out;               // pbv (6291456) + z_pb (24576) fp32
  fused_kernel<<<dim3(780), 128, 0, stream>>>(v, w, out);
}